// Round 3
// baseline (20600.847 us; speedup 1.0000x reference)
//
#include <hip/hip_runtime.h>
#include <cstdint>
#include <cstddef>

// ---------------------------------------------------------------------------
// xLSTM forward, fp32 correctness-first baseline.
// B=4 S=1024 D=1024 I=2048 NHM=4 dh=512 NHS=4 DHS=256 U=1344 K=4 L=256
// Workspace requirement: ~292 MB.
// ---------------------------------------------------------------------------

#define Tz 4096   // B*S

__device__ __forceinline__ float siluf(float x){ return x / (1.f + expf(-x)); }
__device__ __forceinline__ float logsigf(float x){ return fminf(x, 0.f) - log1pf(expf(-fabsf(x))); }

__device__ __forceinline__ float blockReduce256(float v, float* sb){
  int tid = threadIdx.x;
  sb[tid] = v; __syncthreads();
  for (int off = 128; off > 0; off >>= 1){
    if (tid < off) sb[tid] += sb[tid + off];
    __syncthreads();
  }
  float r = sb[0]; __syncthreads();
  return r;
}

// ---------------- embedding gather ----------------
__global__ __launch_bounds__(256) void k_embed(const int* __restrict__ ids,
    const float* __restrict__ emb, float* __restrict__ x){
  int t = blockIdx.x;
  int id = ids[t];
  float4 v = *(const float4*)(emb + (size_t)id*1024 + threadIdx.x*4);
  *(float4*)(x + (size_t)t*1024 + threadIdx.x*4) = v;
}

// ---------------- layer norm over D=1024 ----------------
__global__ __launch_bounds__(256) void k_layernorm(const float* __restrict__ x,
    const float* __restrict__ w, float* __restrict__ y){
  __shared__ float sb[256];
  int t = blockIdx.x, tid = threadIdx.x;
  float4 xv = *(const float4*)(x + (size_t)t*1024 + tid*4);
  float mu = blockReduce256(xv.x+xv.y+xv.z+xv.w, sb) * (1.f/1024.f);
  float4 d = {xv.x-mu, xv.y-mu, xv.z-mu, xv.w-mu};
  float var = blockReduce256(d.x*d.x+d.y*d.y+d.z*d.z+d.w*d.w, sb) * (1.f/1024.f);
  float rstd = 1.f / sqrtf(var + 1e-5f);
  float4 wv = *(const float4*)(w + tid*4);
  float4 o = {d.x*rstd*wv.x, d.y*rstd*wv.y, d.z*rstd*wv.z, d.w*rstd*wv.w};
  *(float4*)(y + (size_t)t*1024 + tid*4) = o;
}

// ---------------- multi-head norm (group G = 512 or 256), in place ----------
__global__ __launch_bounds__(256) void k_mhnorm(float* __restrict__ x,
    const float* __restrict__ w, int G, int rowlen){
  __shared__ float sb[256];
  int t = blockIdx.x, g = blockIdx.y, tid = threadIdx.x;
  float* p = x + (size_t)t*rowlen + g*G;
  float e0 = p[tid];
  float e1 = (G == 512) ? p[tid+256] : 0.f;
  float mu = blockReduce256(e0+e1, sb) / (float)G;
  float d0 = e0-mu, d1 = e1-mu;
  float sq = d0*d0 + ((G==512) ? d1*d1 : 0.f);
  float var = blockReduce256(sq, sb) / (float)G;
  float rstd = 1.f/sqrtf(var + 1e-5f);
  p[tid] = d0*rstd*w[g*G+tid];
  if (G == 512) p[tid+256] = d1*rstd*w[g*G+tid+256];
}

// ---------------- causal depthwise conv (K=4) + silu ----------------
__global__ __launch_bounds__(256) void k_conv_silu(const float* __restrict__ in, int istride,
    int cshift, const float* __restrict__ w, const float* __restrict__ bias,
    float* __restrict__ out, int ostride){
  int idx = blockIdx.x*256 + threadIdx.x;
  int cmask = (1<<cshift) - 1;
  int c = idx & cmask;
  int t = idx >> cshift;
  int b = t >> 10, s = t & 1023;
  float acc = bias[c];
  #pragma unroll
  for (int j=0;j<4;++j){
    int ss = s - 3 + j;
    if (ss >= 0) acc += in[(size_t)((b<<10)+ss)*istride + c] * w[c*4+j];
  }
  out[(size_t)t*ostride + c] = siluf(acc);
}

// ---------------- headwise 4x4 block projection (NB=512) ----------------
__global__ __launch_bounds__(256) void k_headwise(const float* __restrict__ in, int istride,
    const float* __restrict__ w, float* __restrict__ out){
  int idx = blockIdx.x*256 + threadIdx.x;   // Tz*512
  int t = idx >> 9, nb = idx & 511;
  float4 x = *(const float4*)(in + (size_t)t*istride + nb*4);
  const float* wp = w + nb*16;
  float4 r;
  r.x = x.x*wp[0]  + x.y*wp[1]  + x.z*wp[2]  + x.w*wp[3];
  r.y = x.x*wp[4]  + x.y*wp[5]  + x.z*wp[6]  + x.w*wp[7];
  r.z = x.x*wp[8]  + x.y*wp[9]  + x.z*wp[10] + x.w*wp[11];
  r.w = x.x*wp[12] + x.y*wp[13] + x.z*wp[14] + x.w*wp[15];
  *(float4*)(out + (size_t)t*2048 + nb*4) = r;
}

// ---------------- ig/fg gate projections (qkv @ w.T, N=4 heads) ----------
__global__ __launch_bounds__(256) void k_igfg(
  const float* __restrict__ Q, const float* __restrict__ K, const float* __restrict__ V,
  const float* __restrict__ igw, const float* __restrict__ igb,
  const float* __restrict__ fgw, const float* __restrict__ fgb,
  float* __restrict__ ig, float* __restrict__ fg){
  __shared__ float sb[8*256];
  const int t = blockIdx.x, tid = threadIdx.x;
  const int b = t >> 10, s = t & 1023;
  float pig[4] = {0,0,0,0};
  float pfg[4] = {0,0,0,0};
  const size_t base = (size_t)t * 2048;
  for (int i = tid; i < 2048; i += 256){
    float qv = Q[base+i], kv = K[base+i], vv = V[base+i];
    #pragma unroll
    for (int h=0; h<4; ++h){
      const float* wq = igw + h*6144;
      pig[h] += qv*wq[i] + kv*wq[2048+i] + vv*wq[4096+i];
      const float* wf = fgw + h*6144;
      pfg[h] += qv*wf[i] + kv*wf[2048+i] + vv*wf[4096+i];
    }
  }
  #pragma unroll
  for (int h=0;h<4;++h){ sb[h*256+tid] = pig[h]; sb[(4+h)*256+tid] = pfg[h]; }
  __syncthreads();
  if (tid < 8){
    float acc = 0.f;
    for (int j=0;j<256;++j) acc += sb[tid*256+j];
    int h = tid & 3;
    if (tid < 4) ig[(size_t)(b*4+h)*1024 + s] = acc + igb[h];
    else         fg[(size_t)(b*4+h)*1024 + s] = acc + fgb[h];
  }
}

// ---------------- per-(b,h) cumulative log-sigmoid + prefix max ----------
__global__ __launch_bounds__(256) void k_gatescan(const float* __restrict__ fg,
    const float* __restrict__ ig, float* __restrict__ cs, float* __restrict__ pm){
  __shared__ float ls[1024];
  const int bh = blockIdx.x, tid = threadIdx.x;
  for (int s = tid; s < 1024; s += 256) ls[s] = logsigf(fg[bh*1024+s]);
  __syncthreads();
  if (tid == 0){
    float c = 0.f, p = -3.4e38f;
    for (int s=0; s<1024; ++s){
      c += ls[s];
      cs[bh*1024+s] = c;
      float a = ig[bh*1024+s] - c;
      p = fmaxf(p, a);
      pm[bh*1024+s] = p;
    }
  }
}

// ---------------- decay * scores, causal mask, row-normalize (in place) ----
__global__ __launch_bounds__(256) void k_decaynorm(float* __restrict__ SC,
    const float* __restrict__ ig, const float* __restrict__ cs, const float* __restrict__ pm){
  __shared__ float sb[256];
  const int s = blockIdx.x, bh = blockIdx.y;
  const int tid = threadIdx.x;
  const float* igr = ig + bh*1024;
  const float* csr = cs + bh*1024;
  const float cs_s = csr[s];
  const float maxD = cs_s + pm[bh*1024 + s];
  float* row = SC + (size_t)bh*1048576 + (size_t)s*1024;
  float v[4];
  float ssum = 0.f;
  #pragma unroll
  for (int j=0;j<4;++j){
    int t = tid + j*256;
    if (t <= s){
      float d = expf(cs_s - csr[t] + igr[t] - maxD);
      v[j] = row[t] * d;
      ssum += v[j];
    } else v[j] = 0.f;
  }
  float total = blockReduce256(ssum, sb);
  float norm = fmaxf(fabsf(total), expf(-maxD)) + 1e-6f;
  float rn = 1.f / norm;
  #pragma unroll
  for (int j=0;j<4;++j){
    int t = tid + j*256;
    row[t] = v[j] * rn;
  }
}

// ---------------- generic fp32 GEMM, 128x128 tile, batched w/ dual strides --
// C[M,N] = alpha * A[M,K] * op(B) (+C) (+bias);  BT: B is [N,K], else [K,N]
template<bool BT>
__global__ __launch_bounds__(256, 2) void k_gemm(
    const float* __restrict__ A, int lda, long long sA1, long long sA2,
    const float* __restrict__ Bm, int ldb, long long sB1, long long sB2,
    float* __restrict__ C, int ldc, long long sC1, long long sC2,
    int Kd, float alpha, int flags, const float* __restrict__ bias){
  const int z = blockIdx.z;
  const float* Ab = A + (size_t)(z>>2)*sA1 + (size_t)(z&3)*sA2;
  const float* Bb = Bm + (size_t)(z>>2)*sB1 + (size_t)(z&3)*sB2;
  float* Cb = C + (size_t)(z>>2)*sC1 + (size_t)(z&3)*sC2;
  const int tm = blockIdx.y * 128, tn = blockIdx.x * 128;
  __shared__ float As[16][128];
  __shared__ float Bs[16][128];
  const int tid = threadIdx.x;
  const int ty = tid >> 4, tx = tid & 15;
  float acc[8][8];
  #pragma unroll
  for (int i=0;i<8;++i)
    #pragma unroll
    for (int j=0;j<8;++j) acc[i][j] = 0.f;

  for (int k0 = 0; k0 < Kd; k0 += 16){
    #pragma unroll
    for (int jj=0; jj<2; ++jj){
      int fid = tid*2 + jj;
      int row = fid >> 2, kq = fid & 3;
      float4 av = *(const float4*)(Ab + (size_t)(tm+row)*lda + k0 + kq*4);
      As[kq*4+0][row] = av.x; As[kq*4+1][row] = av.y;
      As[kq*4+2][row] = av.z; As[kq*4+3][row] = av.w;
      if (BT){
        float4 bv = *(const float4*)(Bb + (size_t)(tn+row)*ldb + k0 + kq*4);
        Bs[kq*4+0][row] = bv.x; Bs[kq*4+1][row] = bv.y;
        Bs[kq*4+2][row] = bv.z; Bs[kq*4+3][row] = bv.w;
      } else {
        int kr = fid >> 5, nc = fid & 31;
        float4 bv = *(const float4*)(Bb + (size_t)(k0+kr)*ldb + tn + nc*4);
        *(float4*)(&Bs[kr][nc*4]) = bv;
      }
    }
    __syncthreads();
    #pragma unroll
    for (int kk=0; kk<16; ++kk){
      const float4 a0 = *(const float4*)(&As[kk][ty*8]);
      const float4 a1 = *(const float4*)(&As[kk][ty*8+4]);
      const float4 b0 = *(const float4*)(&Bs[kk][tx*8]);
      const float4 b1 = *(const float4*)(&Bs[kk][tx*8+4]);
      const float a[8] = {a0.x,a0.y,a0.z,a0.w,a1.x,a1.y,a1.z,a1.w};
      const float b[8] = {b0.x,b0.y,b0.z,b0.w,b1.x,b1.y,b1.z,b1.w};
      #pragma unroll
      for (int i=0;i<8;++i)
        #pragma unroll
        for (int j=0;j<8;++j)
          acc[i][j] += a[i]*b[j];
    }
    __syncthreads();
  }
  const bool addc = (flags & 1) != 0;
  const bool hasb = (flags & 2) != 0;
  #pragma unroll
  for (int i=0;i<8;++i){
    size_t roff = (size_t)(tm + ty*8 + i)*ldc + tn + tx*8;
    #pragma unroll
    for (int j4=0; j4<8; j4+=4){
      float4 o;
      float* op = (float*)&o;
      #pragma unroll
      for (int j=0;j<4;++j){
        float v = alpha * acc[i][j4+j];
        if (hasb) v += bias[tn + tx*8 + j4 + j];
        if (addc) v += Cb[roff + j4 + j];
        op[j] = v;
      }
      *(float4*)(Cb + roff + j4) = o;
    }
  }
}

// ---------------- mLSTM epilogue: H = (H + skip*xa) * silu(z) ----------
__global__ __launch_bounds__(256) void k_mlstm_epi(float* __restrict__ H,
    const float* __restrict__ XA, const float* __restrict__ UP, const float* __restrict__ skip){
  size_t idx = (size_t)blockIdx.x*256 + threadIdx.x;
  int c = (int)(idx & 2047);
  size_t t = idx >> 11;
  float z = UP[t*4096 + 2048 + c];
  H[idx] = (H[idx] + skip[c]*XA[idx]) * siluf(z);
}

// ---------------- FFN middle: H = gelu(gate) * up ----------------
__global__ __launch_bounds__(256) void k_ffn_mid(const float* __restrict__ UP, float* __restrict__ Hm){
  int idx = blockIdx.x*256 + threadIdx.x;   // Tz*1344
  int t = idx / 1344, u = idx - t*1344;
  float gte = UP[(size_t)t*2688 + u];
  float upp = UP[(size_t)t*2688 + 1344 + u];
  float ge = 0.5f * gte * (1.f + erff(gte * 0.70710678118654752f));
  Hm[idx] = ge * upp;
}

// ---------------- elementwise add ----------------
__global__ __launch_bounds__(256) void k_add(float* __restrict__ x, const float* __restrict__ y){
  size_t i = (size_t)blockIdx.x*256 + threadIdx.x;
  x[i] += y[i];
}

__global__ void k_zero_flags(int* flags){ if (threadIdx.x < 16) flags[threadIdx.x] = 0; }

// ---------------- sLSTM recurrent scan ----------------
// 16 blocks: block q -> head h=q&3, e-quarter q>>2 (64 e-columns).
// Thread tid -> matvec role (g=tid>>6, e-local=tid&63): owns weight column
// rk[h][:, g, e]; 128 d in VGPRs + 128 d in LDS. Gate role (b=tid>>6, e=tid&63)
// keeps c,n,m state in registers. Cross-block h exchange via global hG with
// parity double-buffer + release/acquire flags (skew <= 1 step => safe).
__global__ __launch_bounds__(256, 1) void k_scan(
    const float* __restrict__ pre, const float* __restrict__ rk, const float* __restrict__ rb,
    float* __restrict__ ys, float* __restrict__ hG, int* __restrict__ flags){
  const int q = blockIdx.x;
  const int h = q & 3;
  const int quarter = q >> 2;
  const int tid = threadIdx.x;
  const int g = tid >> 6, el = tid & 63;
  const int e = quarter*64 + el;
  __shared__ float wlds[128][256];
  __shared__ float4 hsh[256];
  __shared__ float rawsh[1088];
  float wreg[128];
  #pragma unroll
  for (int d=0; d<128; ++d)
    wreg[d] = rk[(size_t)((h*256 + d)*4 + g)*256 + e];
  for (int d=0; d<128; ++d)
    wlds[d][tid] = rk[(size_t)((h*256 + 128 + d)*4 + g)*256 + e];
  const float rbv = rb[(h*4+g)*256 + e];
  hsh[tid] = make_float4(0.f,0.f,0.f,0.f);
  __syncthreads();

  const int bb = tid >> 6;
  const int ee = el;
  float c_ = 0.f, n_ = 0.f, m_ = 0.f;
  const float* preB = pre + h*1024 + g*256 + e;
  float* ysB = ys + h*256 + quarter*64 + ee;

  for (int s = 0; s < 1024; ++s){
    float gt0 = preB[(size_t)(s)*4096];
    float gt1 = preB[(size_t)(1024+s)*4096];
    float gt2 = preB[(size_t)(2048+s)*4096];
    float gt3 = preB[(size_t)(3072+s)*4096];
    float4 a0 = make_float4(0.f,0.f,0.f,0.f), a1 = make_float4(0.f,0.f,0.f,0.f);
    #pragma unroll
    for (int d=0; d<128; ++d){
      float4 hv = hsh[d];
      float wv = wreg[d];
      a0.x += hv.x*wv; a0.y += hv.y*wv; a0.z += hv.z*wv; a0.w += hv.w*wv;
    }
    #pragma unroll
    for (int d=0; d<128; ++d){
      float4 hv = hsh[128+d];
      float wv = wlds[d][tid];
      a1.x += hv.x*wv; a1.y += hv.y*wv; a1.z += hv.z*wv; a1.w += hv.w*wv;
    }
    rawsh[el*17 + 0*4 + g] = a0.x + a1.x + gt0 + rbv;
    rawsh[el*17 + 1*4 + g] = a0.y + a1.y + gt1 + rbv;
    rawsh[el*17 + 2*4 + g] = a0.z + a1.z + gt2 + rbv;
    rawsh[el*17 + 3*4 + g] = a0.w + a1.w + gt3 + rbv;
    __syncthreads();
    const float iraw = rawsh[ee*17 + bb*4 + 0];
    const float fraw = rawsh[ee*17 + bb*4 + 1];
    const float zraw = rawsh[ee*17 + bb*4 + 2];
    const float oraw = rawsh[ee*17 + bb*4 + 3];
    const float lfm = m_ + logsigf(fraw);
    const float mnew = fmaxf(iraw, lfm);
    const float igate = expf(iraw - mnew);
    const float fgate = expf(lfm - mnew);
    c_ = fgate*c_ + igate*tanhf(zraw);
    n_ = fgate*n_ + igate;
    m_ = mnew;
    const float hnew = (1.f/(1.f+expf(-oraw))) * c_ / n_;
    ysB[(size_t)((bb<<10)+s)*1024] = hnew;
    const int p = (s+1) & 1;
    hG[((p*4+h)*4+bb)*256 + quarter*64 + ee] = hnew;
    __threadfence();
    __syncthreads();
    if (tid == 0)
      __hip_atomic_store(&flags[q], s+1, __ATOMIC_RELEASE, __HIP_MEMORY_SCOPE_AGENT);
    if (s == 1023) break;
    #pragma unroll
    for (int pb=0; pb<4; ++pb){
      if (pb == quarter) continue;
      const int pq = pb*4 + h;
      while (__hip_atomic_load(&flags[pq], __ATOMIC_ACQUIRE, __HIP_MEMORY_SCOPE_AGENT) < s+1) { }
    }
    #pragma unroll
    for (int jj=0; jj<4; ++jj){
      const int ep = el + jj*64;
      ((float*)hsh)[ep*4 + bb] = hG[((p*4+h)*4+bb)*256 + ep];
    }
    __syncthreads();
  }
}

// ---------------------------------------------------------------------------
extern "C" void kernel_launch(void* const* d_in, const int* in_sizes, int n_in,
                              void* d_out, int out_size, void* d_ws, size_t ws_size,
                              hipStream_t stream){
  const int*   ids       = (const int*)  d_in[0];
  const float* emb       = (const float*)d_in[1];
  const float* m_ln_w    = (const float*)d_in[2];
  const float* m_up_w    = (const float*)d_in[3];
  const float* m_conv_w  = (const float*)d_in[4];
  const float* m_conv_b  = (const float*)d_in[5];
  const float* m_q_w     = (const float*)d_in[6];
  const float* m_k_w     = (const float*)d_in[7];
  const float* m_v_w     = (const float*)d_in[8];
  const float* m_ig_w    = (const float*)d_in[9];
  const float* m_ig_b    = (const float*)d_in[10];
  const float* m_fg_w    = (const float*)d_in[11];
  const float* m_fg_b    = (const float*)d_in[12];
  const float* m_skip    = (const float*)d_in[13];
  const float* m_on_w    = (const float*)d_in[14];
  const float* m_down_w  = (const float*)d_in[15];
  const float* s_ln_w    = (const float*)d_in[16];
  const float* s_conv_w  = (const float*)d_in[17];
  const float* s_conv_b  = (const float*)d_in[18];
  const float* s_iw      = (const float*)d_in[19];
  const float* s_fw      = (const float*)d_in[20];
  const float* s_zw      = (const float*)d_in[21];
  const float* s_ow      = (const float*)d_in[22];
  const float* s_rk      = (const float*)d_in[23];
  const float* s_rb      = (const float*)d_in[24];
  const float* s_gn_w    = (const float*)d_in[25];
  const float* s_ln2_w   = (const float*)d_in[26];
  const float* s_ffn_up  = (const float*)d_in[27];
  const float* s_ffn_dn  = (const float*)d_in[28];
  const float* post_ln_w = (const float*)d_in[29];
  const float* head_w    = (const float*)d_in[30];
  const float* head_b    = (const float*)d_in[31];
  float* out = (float*)d_out;

  float* ws = (float*)d_ws;
  float* X   = ws;                                  // 4096x1024
  float* XN  = X  + (size_t)Tz*1024;                // 4096x1024
  float* UP  = XN + (size_t)Tz*1024;                // 4096x4096 (up / pre-gates / ffn-up)
  float* XA  = UP + (size_t)Tz*4096;                // 4096x2048 (xa / xc)
  float* Q   = XA + (size_t)Tz*2048;                // 4096x2048
  float* Kb  = Q  + (size_t)Tz*2048;                // 4096x2048
  float* Vb  = Kb + (size_t)Tz*2048;                // 4096x2048
  float* SC  = Vb + (size_t)Tz*2048;                // 16 x 1024 x 1024 scores
  float* GIG = SC + (size_t)16*1024*1024;           // ig   (b,h,s)
  float* GFG = GIG + 16384;                         // fg
  float* GCS = GFG + 16384;                         // csum
  float* GPM = GCS + 16384;                         // prefix max of (ig - csum)
  float* HG  = GPM + 16384;                         // scan h exchange [2][4][4][256]
  int*  FLAGS = (int*)(HG + 8192);                  // 16 flags
  float* H = Q;                                     // alias: h / ys / ffn-mid

  const float qk_alpha = 0.044194173824159216f;     // 1/sqrt(512)

  k_embed<<<Tz, 256, 0, stream>>>(ids, emb, X);

  int mi = 0;
  for (int blk = 0; blk < 4; ++blk){
    if (blk == 1){
      // ---------------- sLSTM block ----------------
      k_layernorm<<<Tz, 256, 0, stream>>>(X, s_ln_w, XN);
      k_conv_silu<<<(Tz*1024)/256, 256, 0, stream>>>(XN, 1024, 10, s_conv_w, s_conv_b, XA, 1024);
      // gate projections: per-head 256x256 GEMMs into pre-act buffer UP (b,s,h,g,e)
      dim3 gg(2, 32, 4);
      k_gemm<true><<<gg, 256, 0, stream>>>(XA, 1024, 0, 256, s_iw, 256, 0, 65536,
                                           UP + 0,   4096, 0, 1024, 256, 1.f, 0, nullptr);
      k_gemm<true><<<gg, 256, 0, stream>>>(XA, 1024, 0, 256, s_fw, 256, 0, 65536,
                                           UP + 256, 4096, 0, 1024, 256, 1.f, 0, nullptr);
      k_gemm<true><<<gg, 256, 0, stream>>>(XN, 1024, 0, 256, s_zw, 256, 0, 65536,
                                           UP + 512, 4096, 0, 1024, 256, 1.f, 0, nullptr);
      k_gemm<true><<<gg, 256, 0, stream>>>(XN, 1024, 0, 256, s_ow, 256, 0, 65536,
                                           UP + 768, 4096, 0, 1024, 256, 1.f, 0, nullptr);
      k_zero_flags<<<1, 64, 0, stream>>>(FLAGS);
      k_scan<<<16, 256, 0, stream>>>(UP, s_rk, s_rb, H, HG, FLAGS);
      k_mhnorm<<<dim3(Tz,4), 256, 0, stream>>>(H, s_gn_w, 256, 1024);
      k_add<<<(Tz*1024)/256, 256, 0, stream>>>(X, H);
      k_layernorm<<<Tz, 256, 0, stream>>>(X, s_ln2_w, XN);
      k_gemm<true><<<dim3(21,32,1), 256, 0, stream>>>(XN, 1024, 0, 0, s_ffn_up, 1024, 0, 0,
                                                      UP, 2688, 0, 0, 1024, 1.f, 0, nullptr);
      k_ffn_mid<<<(Tz*1344)/256, 256, 0, stream>>>(UP, H);
      k_gemm<true><<<dim3(8,32,1), 256, 0, stream>>>(H, 1344, 0, 0, s_ffn_dn, 1344, 0, 0,
                                                     X, 1024, 0, 0, 1344, 1.f, 1, nullptr);
    } else {
      // ---------------- mLSTM block (mi = 0,1,2) ----------------
      k_layernorm<<<Tz, 256, 0, stream>>>(X, m_ln_w + (size_t)mi*1024, XN);
      k_gemm<true><<<dim3(32,32,1), 256, 0, stream>>>(XN, 1024, 0, 0,
          m_up_w + (size_t)mi*4096*1024, 1024, 0, 0,
          UP, 4096, 0, 0, 1024, 1.f, 0, nullptr);
      k_conv_silu<<<(Tz*2048)/256, 256, 0, stream>>>(UP, 4096, 11,
          m_conv_w + (size_t)mi*2048*4, m_conv_b + (size_t)mi*2048, XA, 2048);
      k_headwise<<<(Tz*512)/256, 256, 0, stream>>>(XA, 2048, m_q_w + (size_t)mi*8192, Q);
      k_headwise<<<(Tz*512)/256, 256, 0, stream>>>(XA, 2048, m_k_w + (size_t)mi*8192, Kb);
      k_headwise<<<(Tz*512)/256, 256, 0, stream>>>(UP, 4096, m_v_w + (size_t)mi*8192, Vb);
      k_igfg<<<Tz, 256, 0, stream>>>(Q, Kb, Vb,
          m_ig_w + (size_t)mi*4*6144, m_ig_b + (size_t)mi*4,
          m_fg_w + (size_t)mi*4*6144, m_fg_b + (size_t)mi*4, GIG, GFG);
      k_gatescan<<<16, 256, 0, stream>>>(GFG, GIG, GCS, GPM);
      // scores = alpha * Q K^T  (batched over 16 (b,h))
      k_gemm<true><<<dim3(8,8,16), 256, 0, stream>>>(
          Q,  2048, 2097152, 512,  Kb, 2048, 2097152, 512,
          SC, 1024, 4194304, 1048576, 512, qk_alpha, 0, nullptr);
      k_decaynorm<<<dim3(1024,16), 256, 0, stream>>>(SC, GIG, GCS, GPM);
      // H = SCn @ V (NN, batched)
      k_gemm<false><<<dim3(4,8,16), 256, 0, stream>>>(
          SC, 1024, 4194304, 1048576, Vb, 2048, 2097152, 512,
          H,  2048, 2097152, 512, 1024, 1.f, 0, nullptr);
      k_mhnorm<<<dim3(Tz,4), 256, 0, stream>>>(H, m_on_w + (size_t)mi*2048, 512, 2048);
      k_mlstm_epi<<<(Tz*2048)/256, 256, 0, stream>>>(H, XA, UP, m_skip + (size_t)mi*2048);
      k_gemm<true><<<dim3(8,32,1), 256, 0, stream>>>(H, 2048, 0, 0,
          m_down_w + (size_t)mi*1024*2048, 2048, 0, 0,
          X, 1024, 0, 0, 2048, 1.f, 1, nullptr);
      ++mi;
    }
  }
  k_layernorm<<<Tz, 256, 0, stream>>>(X, post_ln_w, XN);
  k_gemm<true><<<dim3(2,32,1), 256, 0, stream>>>(XN, 1024, 0, 0, head_w, 1024, 0, 0,
      out, 256, 0, 0, 1024, 1.f, 2, head_b);
}

// Round 4
// 7751.717 us; speedup vs baseline: 2.6576x; 2.6576x over previous
//
#include <hip/hip_runtime.h>
#include <cstdint>
#include <cstddef>

// ---------------------------------------------------------------------------
// xLSTM forward. fp32 everywhere except sLSTM recurrent matvec (fp16 dot2,
// fp32 accumulate). B=4 S=1024 D=1024 I=2048 NHM=4 NHS=4 DHS=256 U=1344 L=256
// ---------------------------------------------------------------------------

#define Tz 4096   // B*S

typedef _Float16 h2_t __attribute__((ext_vector_type(2)));

__device__ __forceinline__ float siluf(float x){ return x / (1.f + expf(-x)); }
__device__ __forceinline__ float logsigf(float x){ return fminf(x, 0.f) - log1pf(expf(-fabsf(x))); }

__device__ __forceinline__ float fdot2f(uint32_t w, uint32_t h, float acc){
#if __has_builtin(__builtin_amdgcn_fdot2)
  return __builtin_amdgcn_fdot2(__builtin_bit_cast(h2_t, w),
                                __builtin_bit_cast(h2_t, h), acc, false);
#else
  h2_t a = __builtin_bit_cast(h2_t, w), b = __builtin_bit_cast(h2_t, h);
  return acc + (float)a[0]*(float)b[0] + (float)a[1]*(float)b[1];
#endif
}

__device__ __forceinline__ float blockReduce256(float v, float* sb){
  int tid = threadIdx.x;
  sb[tid] = v; __syncthreads();
  for (int off = 128; off > 0; off >>= 1){
    if (tid < off) sb[tid] += sb[tid + off];
    __syncthreads();
  }
  float r = sb[0]; __syncthreads();
  return r;
}

// ---------------- embedding gather ----------------
__global__ __launch_bounds__(256) void k_embed(const int* __restrict__ ids,
    const float* __restrict__ emb, float* __restrict__ x){
  int t = blockIdx.x;
  int id = ids[t];
  float4 v = *(const float4*)(emb + (size_t)id*1024 + threadIdx.x*4);
  *(float4*)(x + (size_t)t*1024 + threadIdx.x*4) = v;
}

// ---------------- layer norm over D=1024 ----------------
__global__ __launch_bounds__(256) void k_layernorm(const float* __restrict__ x,
    const float* __restrict__ w, float* __restrict__ y){
  __shared__ float sb[256];
  int t = blockIdx.x, tid = threadIdx.x;
  float4 xv = *(const float4*)(x + (size_t)t*1024 + tid*4);
  float mu = blockReduce256(xv.x+xv.y+xv.z+xv.w, sb) * (1.f/1024.f);
  float4 d = {xv.x-mu, xv.y-mu, xv.z-mu, xv.w-mu};
  float var = blockReduce256(d.x*d.x+d.y*d.y+d.z*d.z+d.w*d.w, sb) * (1.f/1024.f);
  float rstd = 1.f / sqrtf(var + 1e-5f);
  float4 wv = *(const float4*)(w + tid*4);
  float4 o = {d.x*rstd*wv.x, d.y*rstd*wv.y, d.z*rstd*wv.z, d.w*rstd*wv.w};
  *(float4*)(y + (size_t)t*1024 + tid*4) = o;
}

// ---------------- multi-head norm (group G = 512 or 256), in place ----------
__global__ __launch_bounds__(256) void k_mhnorm(float* __restrict__ x,
    const float* __restrict__ w, int G, int rowlen){
  __shared__ float sb[256];
  int t = blockIdx.x, g = blockIdx.y, tid = threadIdx.x;
  float* p = x + (size_t)t*rowlen + g*G;
  float e0 = p[tid];
  float e1 = (G == 512) ? p[tid+256] : 0.f;
  float mu = blockReduce256(e0+e1, sb) / (float)G;
  float d0 = e0-mu, d1 = e1-mu;
  float sq = d0*d0 + ((G==512) ? d1*d1 : 0.f);
  float var = blockReduce256(sq, sb) / (float)G;
  float rstd = 1.f/sqrtf(var + 1e-5f);
  p[tid] = d0*rstd*w[g*G+tid];
  if (G == 512) p[tid+256] = d1*rstd*w[g*G+tid+256];
}

// ---------------- causal depthwise conv (K=4) + silu ----------------
__global__ __launch_bounds__(256) void k_conv_silu(const float* __restrict__ in, int istride,
    int cshift, const float* __restrict__ w, const float* __restrict__ bias,
    float* __restrict__ out, int ostride){
  int idx = blockIdx.x*256 + threadIdx.x;
  int cmask = (1<<cshift) - 1;
  int c = idx & cmask;
  int t = idx >> cshift;
  int b = t >> 10, s = t & 1023;
  float acc = bias[c];
  #pragma unroll
  for (int j=0;j<4;++j){
    int ss = s - 3 + j;
    if (ss >= 0) acc += in[(size_t)((b<<10)+ss)*istride + c] * w[c*4+j];
  }
  out[(size_t)t*ostride + c] = siluf(acc);
}

// ---------------- headwise 4x4 block projection (NB=512) ----------------
__global__ __launch_bounds__(256) void k_headwise(const float* __restrict__ in, int istride,
    const float* __restrict__ w, float* __restrict__ out){
  int idx = blockIdx.x*256 + threadIdx.x;   // Tz*512
  int t = idx >> 9, nb = idx & 511;
  float4 x = *(const float4*)(in + (size_t)t*istride + nb*4);
  const float* wp = w + nb*16;
  float4 r;
  r.x = x.x*wp[0]  + x.y*wp[1]  + x.z*wp[2]  + x.w*wp[3];
  r.y = x.x*wp[4]  + x.y*wp[5]  + x.z*wp[6]  + x.w*wp[7];
  r.z = x.x*wp[8]  + x.y*wp[9]  + x.z*wp[10] + x.w*wp[11];
  r.w = x.x*wp[12] + x.y*wp[13] + x.z*wp[14] + x.w*wp[15];
  *(float4*)(out + (size_t)t*2048 + nb*4) = r;
}

// ---------------- ig/fg gate projections (qkv @ w.T, N=4 heads) ----------
__global__ __launch_bounds__(256) void k_igfg(
  const float* __restrict__ Q, const float* __restrict__ K, const float* __restrict__ V,
  const float* __restrict__ igw, const float* __restrict__ igb,
  const float* __restrict__ fgw, const float* __restrict__ fgb,
  float* __restrict__ ig, float* __restrict__ fg){
  __shared__ float sb[8*256];
  const int t = blockIdx.x, tid = threadIdx.x;
  const int b = t >> 10, s = t & 1023;
  float pig[4] = {0,0,0,0};
  float pfg[4] = {0,0,0,0};
  const size_t base = (size_t)t * 2048;
  for (int i = tid; i < 2048; i += 256){
    float qv = Q[base+i], kv = K[base+i], vv = V[base+i];
    #pragma unroll
    for (int h=0; h<4; ++h){
      const float* wq = igw + h*6144;
      pig[h] += qv*wq[i] + kv*wq[2048+i] + vv*wq[4096+i];
      const float* wf = fgw + h*6144;
      pfg[h] += qv*wf[i] + kv*wf[2048+i] + vv*wf[4096+i];
    }
  }
  #pragma unroll
  for (int h=0;h<4;++h){ sb[h*256+tid] = pig[h]; sb[(4+h)*256+tid] = pfg[h]; }
  __syncthreads();
  if (tid < 8){
    float acc = 0.f;
    for (int j=0;j<256;++j) acc += sb[tid*256+j];
    int h = tid & 3;
    if (tid < 4) ig[(size_t)(b*4+h)*1024 + s] = acc + igb[h];
    else         fg[(size_t)(b*4+h)*1024 + s] = acc + fgb[h];
  }
}

// ---------------- per-(b,h) cumulative log-sigmoid + prefix max ----------
__global__ __launch_bounds__(256) void k_gatescan(const float* __restrict__ fg,
    const float* __restrict__ ig, float* __restrict__ cs, float* __restrict__ pm){
  __shared__ float ls[1024];
  const int bh = blockIdx.x, tid = threadIdx.x;
  for (int s = tid; s < 1024; s += 256) ls[s] = logsigf(fg[bh*1024+s]);
  __syncthreads();
  if (tid == 0){
    float c = 0.f, p = -3.4e38f;
    for (int s=0; s<1024; ++s){
      c += ls[s];
      cs[bh*1024+s] = c;
      float a = ig[bh*1024+s] - c;
      p = fmaxf(p, a);
      pm[bh*1024+s] = p;
    }
  }
}

// ---------------- decay * scores, causal mask, row-normalize (in place) ----
__global__ __launch_bounds__(256) void k_decaynorm(float* __restrict__ SC,
    const float* __restrict__ ig, const float* __restrict__ cs, const float* __restrict__ pm){
  __shared__ float sb[256];
  const int s = blockIdx.x, bh = blockIdx.y;
  const int tid = threadIdx.x;
  const float* igr = ig + bh*1024;
  const float* csr = cs + bh*1024;
  const float cs_s = csr[s];
  const float maxD = cs_s + pm[bh*1024 + s];
  float* row = SC + (size_t)bh*1048576 + (size_t)s*1024;
  float v[4];
  float ssum = 0.f;
  #pragma unroll
  for (int j=0;j<4;++j){
    int t = tid + j*256;
    if (t <= s){
      float d = expf(cs_s - csr[t] + igr[t] - maxD);
      v[j] = row[t] * d;
      ssum += v[j];
    } else v[j] = 0.f;
  }
  float total = blockReduce256(ssum, sb);
  float norm = fmaxf(fabsf(total), expf(-maxD)) + 1e-6f;
  float rn = 1.f / norm;
  #pragma unroll
  for (int j=0;j<4;++j){
    int t = tid + j*256;
    row[t] = v[j] * rn;
  }
}

// ---------------- generic fp32 GEMM, 128x128 tile, batched w/ dual strides --
// C[M,N] = alpha * A[M,K] * op(B) (+C) (+bias);  BT: B is [N,K], else [K,N]
template<bool BT>
__global__ __launch_bounds__(256, 2) void k_gemm(
    const float* __restrict__ A, int lda, long long sA1, long long sA2,
    const float* __restrict__ Bm, int ldb, long long sB1, long long sB2,
    float* __restrict__ C, int ldc, long long sC1, long long sC2,
    int Kd, float alpha, int flags, const float* __restrict__ bias){
  const int z = blockIdx.z;
  const float* Ab = A + (size_t)(z>>2)*sA1 + (size_t)(z&3)*sA2;
  const float* Bb = Bm + (size_t)(z>>2)*sB1 + (size_t)(z&3)*sB2;
  float* Cb = C + (size_t)(z>>2)*sC1 + (size_t)(z&3)*sC2;
  const int tm = blockIdx.y * 128, tn = blockIdx.x * 128;
  __shared__ float As[16][128];
  __shared__ float Bs[16][128];
  const int tid = threadIdx.x;
  const int ty = tid >> 4, tx = tid & 15;
  float acc[8][8];
  #pragma unroll
  for (int i=0;i<8;++i)
    #pragma unroll
    for (int j=0;j<8;++j) acc[i][j] = 0.f;

  for (int k0 = 0; k0 < Kd; k0 += 16){
    #pragma unroll
    for (int jj=0; jj<2; ++jj){
      int fid = tid*2 + jj;
      int row = fid >> 2, kq = fid & 3;
      float4 av = *(const float4*)(Ab + (size_t)(tm+row)*lda + k0 + kq*4);
      As[kq*4+0][row] = av.x; As[kq*4+1][row] = av.y;
      As[kq*4+2][row] = av.z; As[kq*4+3][row] = av.w;
      if (BT){
        float4 bv = *(const float4*)(Bb + (size_t)(tn+row)*ldb + k0 + kq*4);
        Bs[kq*4+0][row] = bv.x; Bs[kq*4+1][row] = bv.y;
        Bs[kq*4+2][row] = bv.z; Bs[kq*4+3][row] = bv.w;
      } else {
        int kr = fid >> 5, nc = fid & 31;
        float4 bv = *(const float4*)(Bb + (size_t)(k0+kr)*ldb + tn + nc*4);
        *(float4*)(&Bs[kr][nc*4]) = bv;
      }
    }
    __syncthreads();
    #pragma unroll
    for (int kk=0; kk<16; ++kk){
      const float4 a0 = *(const float4*)(&As[kk][ty*8]);
      const float4 a1 = *(const float4*)(&As[kk][ty*8+4]);
      const float4 b0 = *(const float4*)(&Bs[kk][tx*8]);
      const float4 b1 = *(const float4*)(&Bs[kk][tx*8+4]);
      const float a[8] = {a0.x,a0.y,a0.z,a0.w,a1.x,a1.y,a1.z,a1.w};
      const float b[8] = {b0.x,b0.y,b0.z,b0.w,b1.x,b1.y,b1.z,b1.w};
      #pragma unroll
      for (int i=0;i<8;++i)
        #pragma unroll
        for (int j=0;j<8;++j)
          acc[i][j] += a[i]*b[j];
    }
    __syncthreads();
  }
  const bool addc = (flags & 1) != 0;
  const bool hasb = (flags & 2) != 0;
  #pragma unroll
  for (int i=0;i<8;++i){
    size_t roff = (size_t)(tm + ty*8 + i)*ldc + tn + tx*8;
    #pragma unroll
    for (int j4=0; j4<8; j4+=4){
      float4 o;
      float* op = (float*)&o;
      #pragma unroll
      for (int j=0;j<4;++j){
        float v = alpha * acc[i][j4+j];
        if (hasb) v += bias[tn + tx*8 + j4 + j];
        if (addc) v += Cb[roff + j4 + j];
        op[j] = v;
      }
      *(float4*)(Cb + roff + j4) = o;
    }
  }
}

// ---------------- mLSTM epilogue: H = (H + skip*xa) * silu(z) ----------
__global__ __launch_bounds__(256) void k_mlstm_epi(float* __restrict__ H,
    const float* __restrict__ XA, const float* __restrict__ UP, const float* __restrict__ skip){
  size_t idx = (size_t)blockIdx.x*256 + threadIdx.x;
  int c = (int)(idx & 2047);
  size_t t = idx >> 11;
  float z = UP[t*4096 + 2048 + c];
  H[idx] = (H[idx] + skip[c]*XA[idx]) * siluf(z);
}

// ---------------- FFN middle: H = gelu(gate) * up ----------------
__global__ __launch_bounds__(256) void k_ffn_mid(const float* __restrict__ UP, float* __restrict__ Hm){
  int idx = blockIdx.x*256 + threadIdx.x;   // Tz*1344
  int t = idx / 1344, u = idx - t*1344;
  float gte = UP[(size_t)t*2688 + u];
  float upp = UP[(size_t)t*2688 + 1344 + u];
  float ge = 0.5f * gte * (1.f + erff(gte * 0.70710678118654752f));
  Hm[idx] = ge * upp;
}

// ---------------- elementwise add ----------------
__global__ __launch_bounds__(256) void k_add(float* __restrict__ x, const float* __restrict__ y){
  size_t i = (size_t)blockIdx.x*256 + threadIdx.x;
  x[i] += y[i];
}

// ---------------- pack recurrent weights to fp16 pairs ----------------
// rk fp32 [h][d][g][e]  ->  RKH u32 [h][o=g*256+e][j=d/2] (fp16 d-pair)
__global__ __launch_bounds__(256) void k_prep_rk(const float* __restrict__ rk,
    uint32_t* __restrict__ rkh){
  const int bid = blockIdx.x;            // 4h * 4g * 128j = 2048
  const int j = bid & 127, g = (bid>>7)&3, hh = bid>>9;
  const int e = threadIdx.x;
  float r0 = rk[(size_t)((hh*256 + 2*j    )*4 + g)*256 + e];
  float r1 = rk[(size_t)((hh*256 + 2*j + 1)*4 + g)*256 + e];
  h2_t p; p[0] = (_Float16)r0; p[1] = (_Float16)r1;
  rkh[(size_t)(hh*1024 + g*256 + e)*128 + j] = __builtin_bit_cast(uint32_t, p);
}

// ---------------- sLSTM recurrent scan v2: one block per (b,h) chain ------
// 512 threads; thread owns outputs o1=tid (g=tid>>8, e=tid&255) and o2=tid+512
// (g+2, e). Weights fp16-packed: d-pairs 0..91 in VGPRs (2x92), 92..127 in LDS
// ([o][jj] stride 37 -> bank rotation by 5, conflict-free). h broadcast via
// 128-word packed-fp16 LDS buffer; gate exchange via padded rawsh. No
// inter-block communication; 2 barriers/step.
#define JREG 92
#define JLDS 36

__global__ __launch_bounds__(512, 2) void k_scan2(
    const float* __restrict__ pre, const uint32_t* __restrict__ rkh,
    const float* __restrict__ rb, float* __restrict__ ys){
  const int q = blockIdx.x;              // 16 blocks: b = q>>2, h = q&3
  const int b = q >> 2, h = q & 3;
  const int tid = threadIdx.x;
  const int o1 = tid, o2 = tid + 512;
  __shared__ uint32_t wlds[1024*37];     // 148 KiB
  __shared__ float rawsh[256*5];         // 5 KiB
  __shared__ uint32_t hp[128];           // packed h (fp16 pairs)

  const uint32_t* r1 = rkh + (size_t)(h*1024 + o1)*128;
  const uint32_t* r2 = rkh + (size_t)(h*1024 + o2)*128;
  uint32_t wreg1[JREG], wreg2[JREG];
  #pragma unroll
  for (int k = 0; k < JREG/4; ++k){
    uint4 v1 = *(const uint4*)(r1 + k*4);
    uint4 v2 = *(const uint4*)(r2 + k*4);
    wreg1[k*4+0]=v1.x; wreg1[k*4+1]=v1.y; wreg1[k*4+2]=v1.z; wreg1[k*4+3]=v1.w;
    wreg2[k*4+0]=v2.x; wreg2[k*4+1]=v2.y; wreg2[k*4+2]=v2.z; wreg2[k*4+3]=v2.w;
  }
  for (int jj = 0; jj < JLDS; ++jj){
    wlds[o1*37 + jj] = r1[JREG + jj];
    wlds[o2*37 + jj] = r2[JREG + jj];
  }
  if (tid < 128) hp[tid] = 0u;
  const float rb1 = rb[h*1024 + o1];
  const float rb2 = rb[h*1024 + o2];
  float c_ = 0.f, n_ = 0.f, m_ = 0.f;
  const float* preB = pre + (size_t)(b<<10)*4096 + h*1024;
  float* ysB = ys + (size_t)(b<<10)*1024 + h*256;
  const int e = tid & 255, g = tid >> 8;
  __syncthreads();

  for (int s = 0; s < 1024; ++s){
    const float gt1 = preB[(size_t)s*4096 + o1];
    const float gt2 = preB[(size_t)s*4096 + o2];
    float a1 = 0.f, a2 = 0.f;
    #pragma unroll
    for (int k = 0; k < 23; ++k){
      uint4 hc = *(const uint4*)((const uint32_t*)hp + k*4);
      #pragma unroll
      for (int t = 0; t < 4; ++t){
        const int j = k*4 + t;
        const uint32_t hw = (&hc.x)[t];
        a1 = fdot2f(wreg1[j], hw, a1);
        a2 = fdot2f(wreg2[j], hw, a2);
      }
    }
    #pragma unroll
    for (int k = 23; k < 32; ++k){
      uint4 hc = *(const uint4*)((const uint32_t*)hp + k*4);
      #pragma unroll
      for (int t = 0; t < 4; ++t){
        const int jj = k*4 + t - JREG;
        const uint32_t hw = (&hc.x)[t];
        a1 = fdot2f(wlds[o1*37 + jj], hw, a1);
        a2 = fdot2f(wlds[o2*37 + jj], hw, a2);
      }
    }
    rawsh[e*5 + g]     = a1 + gt1 + rb1;
    rawsh[e*5 + g + 2] = a2 + gt2 + rb2;
    __syncthreads();
    if (tid < 256){
      const float iraw = rawsh[tid*5 + 0];
      const float fraw = rawsh[tid*5 + 1];
      const float zraw = rawsh[tid*5 + 2];
      const float oraw = rawsh[tid*5 + 3];
      const float lfm  = m_ + logsigf(fraw);
      const float mnew = fmaxf(iraw, lfm);
      const float ig   = expf(iraw - mnew);
      const float fg   = expf(lfm - mnew);
      c_ = fg*c_ + ig*tanhf(zraw);
      n_ = fg*n_ + ig;
      m_ = mnew;
      const float hnew = (1.f/(1.f+expf(-oraw))) * c_ / n_;
      ysB[(size_t)s*1024 + tid] = hnew;
      ((_Float16*)hp)[tid] = (_Float16)hnew;
    }
    __syncthreads();
  }
}

// ---------------------------------------------------------------------------
extern "C" void kernel_launch(void* const* d_in, const int* in_sizes, int n_in,
                              void* d_out, int out_size, void* d_ws, size_t ws_size,
                              hipStream_t stream){
  const int*   ids       = (const int*)  d_in[0];
  const float* emb       = (const float*)d_in[1];
  const float* m_ln_w    = (const float*)d_in[2];
  const float* m_up_w    = (const float*)d_in[3];
  const float* m_conv_w  = (const float*)d_in[4];
  const float* m_conv_b  = (const float*)d_in[5];
  const float* m_q_w     = (const float*)d_in[6];
  const float* m_k_w     = (const float*)d_in[7];
  const float* m_v_w     = (const float*)d_in[8];
  const float* m_ig_w    = (const float*)d_in[9];
  const float* m_ig_b    = (const float*)d_in[10];
  const float* m_fg_w    = (const float*)d_in[11];
  const float* m_fg_b    = (const float*)d_in[12];
  const float* m_skip    = (const float*)d_in[13];
  const float* m_on_w    = (const float*)d_in[14];
  const float* m_down_w  = (const float*)d_in[15];
  const float* s_ln_w    = (const float*)d_in[16];
  const float* s_conv_w  = (const float*)d_in[17];
  const float* s_conv_b  = (const float*)d_in[18];
  const float* s_iw      = (const float*)d_in[19];
  const float* s_fw      = (const float*)d_in[20];
  const float* s_zw      = (const float*)d_in[21];
  const float* s_ow      = (const float*)d_in[22];
  const float* s_rk      = (const float*)d_in[23];
  const float* s_rb      = (const float*)d_in[24];
  const float* s_gn_w    = (const float*)d_in[25];
  const float* s_ln2_w   = (const float*)d_in[26];
  const float* s_ffn_up  = (const float*)d_in[27];
  const float* s_ffn_dn  = (const float*)d_in[28];
  const float* post_ln_w = (const float*)d_in[29];
  const float* head_w    = (const float*)d_in[30];
  const float* head_b    = (const float*)d_in[31];
  float* out = (float*)d_out;

  float* ws = (float*)d_ws;
  float* X   = ws;                                  // 4096x1024
  float* XN  = X  + (size_t)Tz*1024;                // 4096x1024
  float* UP  = XN + (size_t)Tz*1024;                // 4096x4096 (up / pre-gates / ffn-up)
  float* XA  = UP + (size_t)Tz*4096;                // 4096x2048 (xa / xc)
  float* Q   = XA + (size_t)Tz*2048;                // 4096x2048
  float* Kb  = Q  + (size_t)Tz*2048;                // 4096x2048
  float* Vb  = Kb + (size_t)Tz*2048;                // 4096x2048
  float* SC  = Vb + (size_t)Tz*2048;                // 16 x 1024 x 1024 scores
  float* GIG = SC + (size_t)16*1024*1024;           // ig   (b,h,s)
  float* GFG = GIG + 16384;                         // fg
  float* GCS = GFG + 16384;                         // csum
  float* GPM = GCS + 16384;                         // prefix max of (ig - csum)
  float* H = Q;                                     // alias: h / ys / ffn-mid
  uint32_t* RKH = (uint32_t*)SC;                    // alias: packed fp16 rk (2 MB);
                                                    // SC unused during sLSTM block

  const float qk_alpha = 0.044194173824159216f;     // 1/sqrt(512)

  k_embed<<<Tz, 256, 0, stream>>>(ids, emb, X);

  int mi = 0;
  for (int blk = 0; blk < 4; ++blk){
    if (blk == 1){
      // ---------------- sLSTM block ----------------
      k_prep_rk<<<2048, 256, 0, stream>>>(s_rk, RKH);
      k_layernorm<<<Tz, 256, 0, stream>>>(X, s_ln_w, XN);
      k_conv_silu<<<(Tz*1024)/256, 256, 0, stream>>>(XN, 1024, 10, s_conv_w, s_conv_b, XA, 1024);
      // gate projections: per-head 256x256 GEMMs into pre-act buffer UP (b,s,h,g,e)
      dim3 gg(2, 32, 4);
      k_gemm<true><<<gg, 256, 0, stream>>>(XA, 1024, 0, 256, s_iw, 256, 0, 65536,
                                           UP + 0,   4096, 0, 1024, 256, 1.f, 0, nullptr);
      k_gemm<true><<<gg, 256, 0, stream>>>(XA, 1024, 0, 256, s_fw, 256, 0, 65536,
                                           UP + 256, 4096, 0, 1024, 256, 1.f, 0, nullptr);
      k_gemm<true><<<gg, 256, 0, stream>>>(XN, 1024, 0, 256, s_zw, 256, 0, 65536,
                                           UP + 512, 4096, 0, 1024, 256, 1.f, 0, nullptr);
      k_gemm<true><<<gg, 256, 0, stream>>>(XN, 1024, 0, 256, s_ow, 256, 0, 65536,
                                           UP + 768, 4096, 0, 1024, 256, 1.f, 0, nullptr);
      k_scan2<<<16, 512, 0, stream>>>(UP, RKH, s_rb, H);
      k_mhnorm<<<dim3(Tz,4), 256, 0, stream>>>(H, s_gn_w, 256, 1024);
      k_add<<<(Tz*1024)/256, 256, 0, stream>>>(X, H);
      k_layernorm<<<Tz, 256, 0, stream>>>(X, s_ln2_w, XN);
      k_gemm<true><<<dim3(21,32,1), 256, 0, stream>>>(XN, 1024, 0, 0, s_ffn_up, 1024, 0, 0,
                                                      UP, 2688, 0, 0, 1024, 1.f, 0, nullptr);
      k_ffn_mid<<<(Tz*1344)/256, 256, 0, stream>>>(UP, H);
      k_gemm<true><<<dim3(8,32,1), 256, 0, stream>>>(H, 1344, 0, 0, s_ffn_dn, 1344, 0, 0,
                                                     X, 1024, 0, 0, 1344, 1.f, 1, nullptr);
    } else {
      // ---------------- mLSTM block (mi = 0,1,2) ----------------
      k_layernorm<<<Tz, 256, 0, stream>>>(X, m_ln_w + (size_t)mi*1024, XN);
      k_gemm<true><<<dim3(32,32,1), 256, 0, stream>>>(XN, 1024, 0, 0,
          m_up_w + (size_t)mi*4096*1024, 1024, 0, 0,
          UP, 4096, 0, 0, 1024, 1.f, 0, nullptr);
      k_conv_silu<<<(Tz*2048)/256, 256, 0, stream>>>(UP, 4096, 11,
          m_conv_w + (size_t)mi*2048*4, m_conv_b + (size_t)mi*2048, XA, 2048);
      k_headwise<<<(Tz*512)/256, 256, 0, stream>>>(XA, 2048, m_q_w + (size_t)mi*8192, Q);
      k_headwise<<<(Tz*512)/256, 256, 0, stream>>>(XA, 2048, m_k_w + (size_t)mi*8192, Kb);
      k_headwise<<<(Tz*512)/256, 256, 0, stream>>>(UP, 4096, m_v_w + (size_t)mi*8192, Vb);
      k_igfg<<<Tz, 256, 0, stream>>>(Q, Kb, Vb,
          m_ig_w + (size_t)mi*4*6144, m_ig_b + (size_t)mi*4,
          m_fg_w + (size_t)mi*4*6144, m_fg_b + (size_t)mi*4, GIG, GFG);
      k_gatescan<<<16, 256, 0, stream>>>(GFG, GIG, GCS, GPM);
      // scores = alpha * Q K^T  (batched over 16 (b,h))
      k_gemm<true><<<dim3(8,8,16), 256, 0, stream>>>(
          Q,  2048, 2097152, 512,  Kb, 2048, 2097152, 512,
          SC, 1024, 4194304, 1048576, 512, qk_alpha, 0, nullptr);
      k_decaynorm<<<dim3(1024,16), 256, 0, stream>>>(SC, GIG, GCS, GPM);
      // H = SCn @ V (NN, batched)
      k_gemm<false><<<dim3(4,8,16), 256, 0, stream>>>(
          SC, 1024, 4194304, 1048576, Vb, 2048, 2097152, 512,
          H,  2048, 2097152, 512, 1024, 1.f, 0, nullptr);
      k_mhnorm<<<dim3(Tz,4), 256, 0, stream>>>(H, m_on_w + (size_t)mi*2048, 512, 2048);
      k_mlstm_epi<<<(Tz*2048)/256, 256, 0, stream>>>(H, XA, UP, m_skip + (size_t)mi*2048);
      k_gemm<true><<<dim3(8,32,1), 256, 0, stream>>>(H, 2048, 0, 0,
          m_down_w + (size_t)mi*1024*2048, 2048, 0, 0,
          X, 1024, 0, 0, 2048, 1.f, 1, nullptr);
      ++mi;
    }
  }
  k_layernorm<<<Tz, 256, 0, stream>>>(X, post_ln_w, XN);
  k_gemm<true><<<dim3(2,32,1), 256, 0, stream>>>(XN, 1024, 0, 0, head_w, 1024, 0, 0,
      out, 256, 0, 0, 1024, 1.f, 2, head_b);
}